// Round 3
// baseline (2157.211 us; speedup 1.0000x reference)
//
#include <hip/hip_runtime.h>
#include <stdint.h>

#define DD  128   // D
#define G2D 256   // 2*D
#define G4D 512   // 4*D

typedef float  f32x4  __attribute__((ext_vector_type(4)));
typedef short  s16x8  __attribute__((ext_vector_type(8)));
typedef __bf16 bf16x8 __attribute__((ext_vector_type(8)));

__device__ __forceinline__ short f2bf(float f) {
  unsigned u = __builtin_bit_cast(unsigned, f);
  u += 0x7FFFu + ((u >> 16) & 1u);   // RNE
  return (short)(u >> 16);
}
__device__ __forceinline__ float bf2f(short s) {
  unsigned u = ((unsigned)(unsigned short)s) << 16;
  return __builtin_bit_cast(float, u);
}
__device__ __forceinline__ float sigmoidf_(float x) {
  return 1.f / (1.f + __expf(-x));
}
__device__ __forceinline__ float tanhf_(float x) {
  x = fminf(fmaxf(x, -15.f), 15.f);
  float e = __expf(2.f * x);
  return (e - 1.f) / (e + 1.f);
}

// seg[g] = lower_bound(ind, g) for g in [0..G]; graph_indicator is sorted.
__global__ void seg_kernel(const int* __restrict__ ind, int* __restrict__ seg,
                           int N, int G) {
  int g = blockIdx.x * blockDim.x + threadIdx.x;
  if (g > G) return;
  int lo = 0, hi = N;
  while (lo < hi) {
    int mid = (lo + hi) >> 1;
    if (ind[mid] < g) lo = mid + 1; else hi = mid;
  }
  seg[g] = lo;
}

// WT[n][k] = bf16(W[k][n]); W is [256,512] fp32, WT is [512,256] bf16
__global__ void wconv_kernel(const float* __restrict__ W, short* __restrict__ WT) {
  int idx = blockIdx.x * blockDim.x + threadIdx.x;  // 131072 threads
  int n = idx & (G4D - 1);
  int k = idx >> 9;
  WT[(size_t)n * G2D + k] = f2bf(W[(size_t)k * G4D + n]);
}

// ALL 8 STEPS in one kernel. Block = 16 graphs; carry/mem persist in LDS fp32.
// Per step: each wave runs online-softmax attention for 4 graphs (4x16-lane
// groups, 4 rows/iter), readout -> As bf16; then 16x256 @ 256x512 MFMA GEMM
// + LSTM gates updating carry/mem in LDS. Step 0 reads nf fp32 and writes
// nfb bf16 inline; steps 1-7 re-read nfb (block-local 160KB set -> L2/L3 hot).
__global__ void __launch_bounds__(256) mega_kernel(
    const float* __restrict__ nf, short* __restrict__ nfb,
    const int* __restrict__ seg, const short* __restrict__ WT,
    const float* __restrict__ bias, float* __restrict__ out, int G) {
  __shared__ __align__(16) short As[16][264];   // [carry|readout] bf16 tile
  __shared__ float carryS[16][DD];
  __shared__ float memS[16][DD];
  const int t  = threadIdx.x;
  const int m0 = blockIdx.x * 16;
  #pragma unroll
  for (int i = 0; i < 8; i++) {                  // zero carry/mem (2048 floats)
    int idx = i * 256 + t;
    ((float*)carryS)[idx] = 0.f;
    ((float*)memS)[idx]   = 0.f;
  }
  const int wid  = t >> 6;
  const int lane = t & 63;
  const int gq   = lane >> 4;   // 16-lane group 0..3
  const int sl   = lane & 15;   // features sl*8 .. sl*8+7

  int s0v[4], nv[4];
  #pragma unroll
  for (int q = 0; q < 4; q++) {
    int g = m0 + 4 * wid + q;
    if (g < G) { s0v[q] = seg[g]; nv[q] = seg[g + 1] - s0v[q]; }
    else       { s0v[q] = 0;      nv[q] = 0; }
  }
  __syncthreads();

  for (int step = 0; step < 8; step++) {
    const bool last = (step == 7);
    // ---------- attention: this wave's 4 graphs, one at a time ----------
    for (int q = 0; q < 4; q++) {
      const int row = 4 * wid + q;
      const int g   = m0 + row;
      const int n   = nv[q];
      if (g >= G) continue;                      // wave-uniform
      if (n == 0) {                              // empty graph: readout = 0
        if (gq == 0) {
          #pragma unroll
          for (int k = 0; k < 8; k++) {
            As[row][DD + sl * 8 + k] = 0;
            if (last) out[(size_t)g * G2D + DD + sl * 8 + k] = 0.f;
          }
        }
        continue;
      }
      float c[8];
      #pragma unroll
      for (int k = 0; k < 8; k++) c[k] = carryS[row][sl * 8 + k];
      float m = -1e30f, l = 0.f;
      float acc[8];
      #pragma unroll
      for (int k = 0; k < 8; k++) acc[k] = 0.f;
      const int s0 = s0v[q];

      auto accum = [&](const float* xf) {
        float s = 0.f;
        #pragma unroll
        for (int k = 0; k < 8; k++) s += xf[k] * c[k];
        #pragma unroll
        for (int off = 1; off < 16; off <<= 1) s += __shfl_xor(s, off, 64);
        float nm = fmaxf(m, s);
        float sc = __expf(m - nm);               // exp(-huge)=0 first iter
        float p  = __expf(s - nm);
        l = l * sc + p;
        #pragma unroll
        for (int k = 0; k < 8; k++) acc[k] = acc[k] * sc + p * xf[k];
        m = nm;
      };
      const int nfull = n >> 2;
      const int rem   = n & 3;
      if (step == 0) {                           // fp32 read + bf16 cast/store
        const float* basef = nf  + (size_t)s0 * DD + sl * 8;
        short*       baseb = nfb + (size_t)s0 * DD + sl * 8;
        auto body0 = [&](int j) {
          f32x4 a = *(const f32x4*)(basef + (size_t)j * DD);
          f32x4 b = *(const f32x4*)(basef + (size_t)j * DD + 4);
          s16x8 xr;
          xr[0]=f2bf(a.x); xr[1]=f2bf(a.y); xr[2]=f2bf(a.z); xr[3]=f2bf(a.w);
          xr[4]=f2bf(b.x); xr[5]=f2bf(b.y); xr[6]=f2bf(b.z); xr[7]=f2bf(b.w);
          *(s16x8*)(baseb + (size_t)j * DD) = xr;
          float xf[8];
          #pragma unroll
          for (int k = 0; k < 8; k++) xf[k] = bf2f(xr[k]);
          accum(xf);
        };
        #pragma unroll 2
        for (int i = 0; i < nfull; i++) body0(i * 4 + gq);
        if (gq < rem) body0(nfull * 4 + gq);
      } else {                                   // bf16 re-read (L2/L3 hot)
        const short* baseb = nfb + (size_t)s0 * DD + sl * 8;
        auto body1 = [&](int j) {
          s16x8 xr = *(const s16x8*)(baseb + (size_t)j * DD);
          float xf[8];
          #pragma unroll
          for (int k = 0; k < 8; k++) xf[k] = bf2f(xr[k]);
          accum(xf);
        };
        #pragma unroll 2
        for (int i = 0; i < nfull; i++) body1(i * 4 + gq);
        if (gq < rem) body1(nfull * 4 + gq);
      }
      // merge the 4 group states (xor 16, then xor 32)
      #pragma unroll
      for (int w = 16; w <= 32; w <<= 1) {
        float m2 = __shfl_xor(m, w, 64);
        float l2 = __shfl_xor(l, w, 64);
        float M  = fmaxf(m, m2);
        float e1 = __expf(m - M);
        float e2 = __expf(m2 - M);
        l = l * e1 + l2 * e2;
        #pragma unroll
        for (int k = 0; k < 8; k++) {
          float a2 = __shfl_xor(acc[k], w, 64);
          acc[k] = acc[k] * e1 + a2 * e2;
        }
        m = M;
      }
      if (gq == 0) {
        float inv = 1.f / l;                     // l > 0 since n >= 1
        #pragma unroll
        for (int k = 0; k < 8; k++) {
          float r = acc[k] * inv;
          As[row][DD + sl * 8 + k] = f2bf(r);
          if (last) out[(size_t)g * G2D + DD + sl * 8 + k] = r;
        }
      }
    }
    // ---------- carry -> As bf16 (steps 0-6) / carry -> out (step 7) ------
    {
      int row = t >> 4;
      int c0  = (t & 15) * 8;
      int g   = m0 + row;
      if (!last) {
        #pragma unroll
        for (int k = 0; k < 8; k++) As[row][c0 + k] = f2bf(carryS[row][c0 + k]);
      } else if (g < G) {
        #pragma unroll
        for (int k = 0; k < 8; k++)
          out[(size_t)g * G2D + c0 + k] = carryS[row][c0 + k];
      }
    }
    if (last) break;
    __syncthreads();
    // ---------- GEMM z = As @ WT + b, LSTM gates, update carry/mem --------
    {
      const int cb = wid * 32;
      f32x4 acc2[4][2];
      #pragma unroll
      for (int gi = 0; gi < 4; gi++)
        #pragma unroll
        for (int ns = 0; ns < 2; ns++) { f32x4 z = {0.f,0.f,0.f,0.f}; acc2[gi][ns] = z; }
      #pragma unroll
      for (int kc = 0; kc < 8; kc++) {
        int k0 = kc * 32 + gq * 8;
        s16x8 a = *(const s16x8*)(&As[sl][k0]);
        #pragma unroll
        for (int gi = 0; gi < 4; gi++) {
          #pragma unroll
          for (int ns = 0; ns < 2; ns++) {
            int ncol = gi * DD + cb + ns * 16 + sl;
            s16x8 b = *(const s16x8*)(WT + (size_t)ncol * G2D + k0);
            acc2[gi][ns] = __builtin_amdgcn_mfma_f32_16x16x32_bf16(
                __builtin_bit_cast(bf16x8, a), __builtin_bit_cast(bf16x8, b),
                acc2[gi][ns], 0, 0, 0);
          }
        }
      }
      // C/D layout: col = lane&15, row = quad*4 + reg
      #pragma unroll
      for (int ns = 0; ns < 2; ns++) {
        int col = cb + ns * 16 + sl;
        float bu = bias[0 * DD + col];
        float bf = bias[1 * DD + col];
        float bc = bias[2 * DD + col];
        float bo = bias[3 * DD + col];
        #pragma unroll
        for (int r = 0; r < 4; r++) {
          int row = gq * 4 + r;
          int g   = m0 + row;
          if (g < G) {
            float u = acc2[0][ns][r] + bu;
            float f = acc2[1][ns][r] + bf;
            float c = acc2[2][ns][r] + bc;
            float o = acc2[3][ns][r] + bo;
            float mo = memS[row][col];
            float mn = sigmoidf_(f) * mo + sigmoidf_(u) * tanhf_(c);
            memS[row][col]   = mn;
            carryS[row][col] = sigmoidf_(o) * tanhf_(mn);
          }
        }
      }
    }
    __syncthreads();
  }
}

extern "C" void kernel_launch(void* const* d_in, const int* in_sizes, int n_in,
                              void* d_out, int out_size, void* d_ws, size_t ws_size,
                              hipStream_t stream) {
  const float* nf   = (const float*)d_in[0];
  const int*   ind  = (const int*)d_in[1];
  const float* W    = (const float*)d_in[2];
  const float* bias = (const float*)d_in[3];
  int N = in_sizes[1];
  int G = out_size / G2D;   // 25000

  char* ws = (char*)d_ws;
  size_t off = 0;
  short* nfb = (short*)(ws + off); off += (size_t)N * DD * 2;    // nf bf16
  short* WT  = (short*)(ws + off); off += (size_t)G2D * G4D * 2; // W^T bf16
  int*   seg = (int*)(ws + off);   off += (size_t)(G + 1) * 4;
  (void)ws_size; (void)n_in;

  seg_kernel<<<(G + 256) / 256, 256, 0, stream>>>(ind, seg, N, G);
  wconv_kernel<<<(G2D * G4D) / 256, 256, 0, stream>>>(W, WT);
  mega_kernel<<<(G + 15) / 16, 256, 0, stream>>>(nf, nfb, seg, WT, bias,
                                                 (float*)d_out, G);
}

// Round 4
// 1812.958 us; speedup vs baseline: 1.1899x; 1.1899x over previous
//
#include <hip/hip_runtime.h>
#include <stdint.h>

#define DD  128   // D
#define G2D 256   // 2*D
#define G4D 512   // 4*D

typedef float  f32x4  __attribute__((ext_vector_type(4)));
typedef short  s16x8  __attribute__((ext_vector_type(8)));
typedef __bf16 bf16x8 __attribute__((ext_vector_type(8)));

__device__ __forceinline__ short f2bf(float f) {
  unsigned u = __builtin_bit_cast(unsigned, f);
  u += 0x7FFFu + ((u >> 16) & 1u);   // RNE
  return (short)(u >> 16);
}
__device__ __forceinline__ float bf2f(short s) {
  unsigned u = ((unsigned)(unsigned short)s) << 16;
  return __builtin_bit_cast(float, u);
}
__device__ __forceinline__ float sigmoidf_(float x) {
  return 1.f / (1.f + __expf(-x));
}
__device__ __forceinline__ float tanhf_(float x) {
  x = fminf(fmaxf(x, -15.f), 15.f);
  float e = __expf(2.f * x);
  return (e - 1.f) / (e + 1.f);
}

// seg[g] = lower_bound(ind, g) for g in [0..G]; graph_indicator is sorted.
__global__ void seg_kernel(const int* __restrict__ ind, int* __restrict__ seg,
                           int N, int G) {
  int g = blockIdx.x * blockDim.x + threadIdx.x;
  if (g > G) return;
  int lo = 0, hi = N;
  while (lo < hi) {
    int mid = (lo + hi) >> 1;
    if (ind[mid] < g) lo = mid + 1; else hi = mid;
  }
  seg[g] = lo;
}

// WT[n][k] = bf16(W[k][n]); W is [256,512] fp32, WT is [512,256] bf16
__global__ void wconv_kernel(const float* __restrict__ W, short* __restrict__ WT) {
  int idx = blockIdx.x * blockDim.x + threadIdx.x;  // 131072 threads
  int n = idx & (G4D - 1);
  int k = idx >> 9;
  WT[(size_t)n * G2D + k] = f2bf(W[(size_t)k * G4D + n]);
}

// ALL 8 STEPS fused. Block = 16 graphs; carry/mem persist in LDS fp32.
// Pre-pass: each wave converts its 4 graphs' nodes fp32->bf16 into nfb
// (same wave reads them back -> ordering guaranteed by compiler).
// Attention: per wave per graph, 4 rows/batch with explicit next-batch
// prefetch (>=8 x 1KB wave-loads in flight -> MLP-bound no more).
// Then 16x256 @ 256x512 MFMA GEMM + LSTM gates in LDS.
__global__ void __launch_bounds__(256, 3) mega_kernel(
    const float* __restrict__ nf, short* __restrict__ nfb,
    const int* __restrict__ seg, const short* __restrict__ WT,
    const float* __restrict__ bias, float* __restrict__ out, int G) {
  __shared__ __align__(16) short As[16][272];     // [carry|readout] bf16 tile
  __shared__ float carryS[16][132];               // +4 pad: bank spread
  __shared__ float memS[16][132];
  const int t  = threadIdx.x;
  const int m0 = blockIdx.x * 16;
  for (int idx = t; idx < 16 * 132; idx += 256) {
    ((float*)carryS)[idx] = 0.f;
    ((float*)memS)[idx]   = 0.f;
  }
  const int wid  = t >> 6;
  const int lane = t & 63;
  const int gq   = lane >> 4;   // 16-lane group 0..3 (row-within-quad)
  const int sl   = lane & 15;   // features sl*8 .. sl*8+7

  int s0v[4], nv[4];
  #pragma unroll
  for (int q = 0; q < 4; q++) {
    int g = m0 + 4 * wid + q;
    if (g < G) { s0v[q] = seg[g]; nv[q] = seg[g + 1] - s0v[q]; }
    else       { s0v[q] = 0;      nv[q] = 0; }
  }

  // hoisted bias (loop-invariant): [ns][gate]
  float br[2][4];
  #pragma unroll
  for (int ns = 0; ns < 2; ns++) {
    int col = wid * 32 + ns * 16 + sl;
    #pragma unroll
    for (int gi = 0; gi < 4; gi++) br[ns][gi] = bias[gi * DD + col];
  }

  // ---- pre-pass: fp32 -> bf16 conversion of this wave's graphs ----
  #pragma unroll 1
  for (int q = 0; q < 4; q++) {
    int g = m0 + 4 * wid + q;
    if (g >= G) continue;
    int n = nv[q];
    const float* basef = nf  + (size_t)s0v[q] * DD + sl * 8;
    short*       baseb = nfb + (size_t)s0v[q] * DD + sl * 8;
    #pragma unroll 2
    for (int jb = 0; jb < n; jb += 4) {
      int j = jb + gq;
      if (j < n) {
        f32x4 a = *(const f32x4*)(basef + (size_t)j * DD);
        f32x4 b = *(const f32x4*)(basef + (size_t)j * DD + 4);
        s16x8 xr;
        xr[0]=f2bf(a.x); xr[1]=f2bf(a.y); xr[2]=f2bf(a.z); xr[3]=f2bf(a.w);
        xr[4]=f2bf(b.x); xr[5]=f2bf(b.y); xr[6]=f2bf(b.z); xr[7]=f2bf(b.w);
        *(s16x8*)(baseb + (size_t)j * DD) = xr;
      }
    }
  }
  __syncthreads();

  for (int step = 0; step < 8; step++) {
    const bool last = (step == 7);
    // ---------- attention: this wave's 4 graphs, one at a time ----------
    #pragma unroll 1
    for (int q = 0; q < 4; q++) {
      const int row = 4 * wid + q;
      const int g   = m0 + row;
      const int n   = nv[q];
      if (g >= G) continue;                      // wave-uniform
      if (n == 0) {                              // empty graph: readout = 0
        if (gq == 0) {
          #pragma unroll
          for (int k = 0; k < 8; k++) {
            As[row][DD + sl * 8 + k] = 0;
            if (last) out[(size_t)g * G2D + DD + sl * 8 + k] = 0.f;
          }
        }
        continue;
      }
      float c[8];
      #pragma unroll
      for (int k = 0; k < 8; k++) c[k] = carryS[row][sl * 8 + k];
      float m = -1e30f, l = 0.f;
      float acc[8];
      #pragma unroll
      for (int k = 0; k < 8; k++) acc[k] = 0.f;
      const short* baseb = nfb + (size_t)s0v[q] * DD + sl * 8;

      auto accum = [&](s16x8 xr) {
        float xf[8];
        #pragma unroll
        for (int k = 0; k < 8; k++) xf[k] = bf2f(xr[k]);
        float s = 0.f;
        #pragma unroll
        for (int k = 0; k < 8; k++) s += xf[k] * c[k];
        #pragma unroll
        for (int off = 1; off < 16; off <<= 1) s += __shfl_xor(s, off, 64);
        float nm = fmaxf(m, s);
        float sc = __expf(m - nm);               // exp(-huge)=0 first iter
        float p  = __expf(s - nm);
        l = l * sc + p;
        #pragma unroll
        for (int k = 0; k < 8; k++) acc[k] = acc[k] * sc + p * xf[k];
        m = nm;
      };

      // main: batches of 16 rows (4 per group), prefetch next batch
      const int nb = n >> 4;
      s16x8 cur[4];
      if (nb > 0) {
        #pragma unroll
        for (int r = 0; r < 4; r++)
          cur[r] = *(const s16x8*)(baseb + (size_t)(gq + r * 4) * DD);
      }
      #pragma unroll 1
      for (int ib = 0; ib + 1 < nb; ib++) {
        s16x8 nxt[4];
        #pragma unroll
        for (int r = 0; r < 4; r++)
          nxt[r] = *(const s16x8*)(baseb + (size_t)((ib + 1) * 16 + gq + r * 4) * DD);
        #pragma unroll
        for (int r = 0; r < 4; r++) accum(cur[r]);
        #pragma unroll
        for (int r = 0; r < 4; r++) cur[r] = nxt[r];
      }
      if (nb > 0) {
        #pragma unroll
        for (int r = 0; r < 4; r++) accum(cur[r]);
      }
      // tail: rows nb*16 .. n-1
      const int done = nb << 4;
      const int remn = n - done;
      const int nt = remn >> 2;
      #pragma unroll 1
      for (int i = 0; i < nt; i++) {
        s16x8 rr = *(const s16x8*)(baseb + (size_t)(done + i * 4 + gq) * DD);
        accum(rr);
      }
      const int r2 = remn & 3;
      if (gq < r2) {
        s16x8 rr = *(const s16x8*)(baseb + (size_t)(done + nt * 4 + gq) * DD);
        accum(rr);
      }
      // merge the 4 group states (xor 16, then xor 32)
      #pragma unroll
      for (int w = 16; w <= 32; w <<= 1) {
        float m2 = __shfl_xor(m, w, 64);
        float l2 = __shfl_xor(l, w, 64);
        float M  = fmaxf(m, m2);
        float e1 = __expf(m - M);
        float e2 = __expf(m2 - M);
        l = l * e1 + l2 * e2;
        #pragma unroll
        for (int k = 0; k < 8; k++) {
          float a2 = __shfl_xor(acc[k], w, 64);
          acc[k] = acc[k] * e1 + a2 * e2;
        }
        m = M;
      }
      if (gq == 0) {
        float inv = 1.f / l;                     // l > 0 since n >= 1
        #pragma unroll
        for (int k = 0; k < 8; k++) {
          float r = acc[k] * inv;
          As[row][DD + sl * 8 + k] = f2bf(r);
          if (last) out[(size_t)g * G2D + DD + sl * 8 + k] = r;
        }
      }
    }
    // ---------- carry -> As bf16 (steps 0-6) / carry -> out (step 7) ------
    {
      int row = t >> 4;
      int c0  = (t & 15) * 8;
      int g   = m0 + row;
      if (!last) {
        #pragma unroll
        for (int k = 0; k < 8; k++) As[row][c0 + k] = f2bf(carryS[row][c0 + k]);
      } else if (g < G) {
        #pragma unroll
        for (int k = 0; k < 8; k++)
          out[(size_t)g * G2D + c0 + k] = carryS[row][c0 + k];
      }
    }
    if (last) break;
    __syncthreads();
    // ---------- GEMM z = As @ WT + b, LSTM gates, update carry/mem --------
    {
      const int cb = wid * 32;
      f32x4 acc2[4][2];
      #pragma unroll
      for (int gi = 0; gi < 4; gi++)
        #pragma unroll
        for (int ns = 0; ns < 2; ns++) { f32x4 z = {0.f,0.f,0.f,0.f}; acc2[gi][ns] = z; }
      #pragma unroll
      for (int kc = 0; kc < 8; kc++) {
        int k0 = kc * 32 + gq * 8;
        s16x8 a = *(const s16x8*)(&As[sl][k0]);
        #pragma unroll
        for (int gi = 0; gi < 4; gi++) {
          #pragma unroll
          for (int ns = 0; ns < 2; ns++) {
            int ncol = gi * DD + cb + ns * 16 + sl;
            s16x8 b = *(const s16x8*)(WT + (size_t)ncol * G2D + k0);
            acc2[gi][ns] = __builtin_amdgcn_mfma_f32_16x16x32_bf16(
                __builtin_bit_cast(bf16x8, a), __builtin_bit_cast(bf16x8, b),
                acc2[gi][ns], 0, 0, 0);
          }
        }
      }
      // C/D layout: col = lane&15, row = quad*4 + reg
      #pragma unroll
      for (int ns = 0; ns < 2; ns++) {
        int col = cb + ns * 16 + sl;
        #pragma unroll
        for (int r = 0; r < 4; r++) {
          int row = gq * 4 + r;
          int g   = m0 + row;
          if (g < G) {
            float u = acc2[0][ns][r] + br[ns][0];
            float f = acc2[1][ns][r] + br[ns][1];
            float c = acc2[2][ns][r] + br[ns][2];
            float o = acc2[3][ns][r] + br[ns][3];
            float mo = memS[row][col];
            float mn = sigmoidf_(f) * mo + sigmoidf_(u) * tanhf_(c);
            memS[row][col]   = mn;
            carryS[row][col] = sigmoidf_(o) * tanhf_(mn);
          }
        }
      }
    }
    __syncthreads();
  }
}

extern "C" void kernel_launch(void* const* d_in, const int* in_sizes, int n_in,
                              void* d_out, int out_size, void* d_ws, size_t ws_size,
                              hipStream_t stream) {
  const float* nf   = (const float*)d_in[0];
  const int*   ind  = (const int*)d_in[1];
  const float* W    = (const float*)d_in[2];
  const float* bias = (const float*)d_in[3];
  int N = in_sizes[1];
  int G = out_size / G2D;   // 25000

  char* ws = (char*)d_ws;
  size_t off = 0;
  short* nfb = (short*)(ws + off); off += (size_t)N * DD * 2;    // nf bf16
  short* WT  = (short*)(ws + off); off += (size_t)G2D * G4D * 2; // W^T bf16
  int*   seg = (int*)(ws + off);   off += (size_t)(G + 1) * 4;
  (void)ws_size; (void)n_in;

  seg_kernel<<<(G + 256) / 256, 256, 0, stream>>>(ind, seg, N, G);
  wconv_kernel<<<(G2D * G4D) / 256, 256, 0, stream>>>(W, WT);
  mega_kernel<<<(G + 15) / 16, 256, 0, stream>>>(nf, nfb, seg, WT, bias,
                                                 (float*)d_out, G);
}